// Round 4
// baseline (153.449 us; speedup 1.0000x reference)
//
#include <hip/hip_runtime.h>
#include <math.h>

// Fixed-size problem: B = 4194304
#define BTOT 4194304
#define TPB  256
#define EPT  16                 // elements per thread
#define CS   (TPB * EPT)        // 4096 elements per chunk/block
#define NCH  (BTOT / CS)        // 1024 chunks
#define CPT  (NCH / TPB)        // 4 chunks per thread in the chunk-scan

// ws layout (floats): 9 arrays of NCH chunk summaries
//  0:Pv 1:Sv 2:Pa 3:Sa 4:sL 5:sq 6:sL2 7:sLq 8:sq2

__constant__ const float kG  = 0.99f;
__constant__ const float kGT = 0.99f * 0.95f;

typedef float f4v __attribute__((ext_vector_type(4)));

__device__ __forceinline__ float wave_redf(float x) {
#pragma unroll
    for (int o = 32; o > 0; o >>= 1) x += __shfl_down(x, o);
    return x;
}
__device__ __forceinline__ double wave_redd(double x) {
#pragma unroll
    for (int o = 32; o > 0; o >>= 1) x += __shfl_down(x, o);
    return x;
}

// Block-wide suffix scan of affine pairs (P,S) for both recurrences, via
// wave shuffles + one small LDS combine (2 barriers total, no 4KB ping-pong).
// Affine map of thread j: x_right -> S + P * x_right.
// Returns:
//   (cpv,csv,cpa,csa) = composition of threads j+1..TPB-1 (identity at j=255)
//   (tpv,tsv,tpa,tsa) = composition of ALL TPB threads (chunk total)
__device__ __forceinline__ void block_suffix_affine(
    float pv, float sv, float pa, float sa, int j,
    float& cpv, float& csv, float& cpa, float& csa,
    float& tpv, float& tsv, float& tpa, float& tsa)
{
    const int ln = j & 63, w = j >> 6;
    __shared__ float wt[4][4];
    __syncthreads();                       // protect wt across repeated calls

    // wave-level inclusive suffix scan (lane ln ends covering ln..63)
#pragma unroll
    for (int o = 1; o < 64; o <<= 1) {
        float qpv = __shfl_down(pv, o), qsv = __shfl_down(sv, o);
        float qpa = __shfl_down(pa, o), qsa = __shfl_down(sa, o);
        if (ln + o < 64) { sv += pv * qsv; pv *= qpv; sa += pa * qsa; pa *= qpa; }
    }
    // exclusive-from-right (lanes ln+1..63)
    float epv = __shfl_down(pv, 1), esv = __shfl_down(sv, 1);
    float epa = __shfl_down(pa, 1), esa = __shfl_down(sa, 1);
    if (ln == 63) { epv = 1.f; esv = 0.f; epa = 1.f; esa = 0.f; }

    if (ln == 0) { wt[w][0] = pv; wt[w][1] = sv; wt[w][2] = pa; wt[w][3] = sa; }
    __syncthreads();

    // rest = totals of waves w+1..3, composed right-to-left
    float rpv = 1.f, rsv = 0.f, rpa = 1.f, rsa = 0.f;
    for (int u = 3; u > w; --u) {
        rsv = wt[u][1] + wt[u][0] * rsv; rpv = wt[u][0] * rpv;
        rsa = wt[u][3] + wt[u][2] * rsa; rpa = wt[u][2] * rpa;
    }
    csv = esv + epv * rsv; cpv = epv * rpv;
    csa = esa + epa * rsa; cpa = epa * rpa;

    // block total = wt[0] o wt[1] o wt[2] o wt[3]
    float t0pv = 1.f, t0sv = 0.f, t0pa = 1.f, t0sa = 0.f;
#pragma unroll
    for (int u = 3; u >= 0; --u) {
        t0sv = wt[u][1] + wt[u][0] * t0sv; t0pv = wt[u][0] * t0pv;
        t0sa = wt[u][3] + wt[u][2] * t0sa; t0pa = wt[u][2] * t0pa;
    }
    tpv = t0pv; tsv = t0sv; tpa = t0pa; tsa = t0sa;
}

// ---------------- K1: per-chunk affine summaries + quadratic stats ---------
__global__ __launch_bounds__(TPB) void ppo_k1_summarize(
    const float* __restrict__ r, const float* __restrict__ v,
    const int* __restrict__ mk, float* __restrict__ ws) {
    const int c = blockIdx.x;
    const int j = threadIdx.x;
    const int base = c * CS + j * EPT;

    float rr[EPT], vv[EPT + 1], dd[EPT];
    int mm[EPT];
    const float4* r4 = (const float4*)(r + base);
    const float4* v4 = (const float4*)(v + base);
    const int4*   m4 = (const int4*)(mk + base);
#pragma unroll
    for (int k = 0; k < EPT / 4; ++k) {
        float4 a = r4[k];
        rr[4*k] = a.x; rr[4*k+1] = a.y; rr[4*k+2] = a.z; rr[4*k+3] = a.w;
        float4 b = v4[k];
        vv[4*k] = b.x; vv[4*k+1] = b.y; vv[4*k+2] = b.z; vv[4*k+3] = b.w;
        int4 m = m4[k];
        mm[4*k] = m.x; mm[4*k+1] = m.y; mm[4*k+2] = m.z; mm[4*k+3] = m.w;
    }
    vv[EPT] = (base + EPT < BTOT) ? v[base + EPT] : 0.0f;

#pragma unroll
    for (int k = 0; k < EPT; ++k) {
        float m = (float)mm[k];
        dd[k] = rr[k] + kG * m * vv[k + 1] - vv[k];
    }

    // per-thread affine summaries (reverse, zero carry)
    float pv = 1.0f, sv = 0.0f, pa = 1.0f, sa = 0.0f;
#pragma unroll
    for (int k = EPT - 1; k >= 0; --k) {
        float m = (float)mm[k];
        float av = kG * m, aa = kGT * m;
        sv = rr[k] + av * sv;
        sa = dd[k] + aa * sa;
        pv *= av; pa *= aa;
    }

    float QrV, CinV, QrA, CinA, chPv, chSv, chPa, chSa;
    block_suffix_affine(pv, sv, pa, sa, j,
                        QrV, CinV, QrA, CinA, chPv, chSv, chPa, chSa);

    // chunk-local A values + quadratic stats: A = L + q * C_chunk
    float x = CinA, ql = 1.0f;
    float s0 = 0, s1 = 0, s2 = 0, s3 = 0, s4 = 0;
#pragma unroll
    for (int k = EPT - 1; k >= 0; --k) {
        float m = (float)mm[k];
        float aa = kGT * m;
        x = dd[k] + aa * x;
        ql *= aa;
        float q = ql * QrA;
        s0 += x; s1 += q; s2 += x * x; s3 += x * q; s4 += q * q;
    }
    s0 = wave_redf(s0); s1 = wave_redf(s1); s2 = wave_redf(s2);
    s3 = wave_redf(s3); s4 = wave_redf(s4);
    __shared__ float rb[4][5];
    int wid = j >> 6, ln = j & 63;
    if (ln == 0) { rb[wid][0]=s0; rb[wid][1]=s1; rb[wid][2]=s2; rb[wid][3]=s3; rb[wid][4]=s4; }
    __syncthreads();
    if (j == 0) {
        float t0=0,t1=0,t2=0,t3=0,t4=0;
        for (int w = 0; w < 4; ++w) { t0+=rb[w][0]; t1+=rb[w][1]; t2+=rb[w][2]; t3+=rb[w][3]; t4+=rb[w][4]; }
        ws[0*NCH+c] = chPv; ws[1*NCH+c] = chSv; ws[2*NCH+c] = chPa; ws[3*NCH+c] = chSa;
        ws[4*NCH+c] = t0;   ws[5*NCH+c] = t1;   ws[6*NCH+c] = t2;
        ws[7*NCH+c] = t3;   ws[8*NCH+c] = t4;
    }
}

// ------- K2: every block redundantly scans chunk summaries, then finalizes
//         its own chunk (inputs re-read, L3-resident). No grid sync. --------
__global__ __launch_bounds__(TPB) void ppo_k2_finalize(
    const float* __restrict__ r, const float* __restrict__ v,
    const int* __restrict__ mk, const float* __restrict__ ws,
    float* __restrict__ outA, float* __restrict__ outV)
{
    const int c = blockIdx.x;
    const int j = threadIdx.x;
    const int base = c * CS + j * EPT;

    __shared__ double rd[4][2];
    __shared__ float bcast[4];   // 0:carryV(into chunk c) 1:carryA 2:mean 3:inv_std

    // ---- redundant chunk-summary scan (identical in every block) ----
    {
        float cpv[CPT], csv[CPT], cpa[CPT], csa[CPT];
        {
            float4 t;
            t = *(const float4*)(ws + 0*NCH + 4*j); cpv[0]=t.x; cpv[1]=t.y; cpv[2]=t.z; cpv[3]=t.w;
            t = *(const float4*)(ws + 1*NCH + 4*j); csv[0]=t.x; csv[1]=t.y; csv[2]=t.z; csv[3]=t.w;
            t = *(const float4*)(ws + 2*NCH + 4*j); cpa[0]=t.x; cpa[1]=t.y; cpa[2]=t.z; cpa[3]=t.w;
            t = *(const float4*)(ws + 3*NCH + 4*j); csa[0]=t.x; csa[1]=t.y; csa[2]=t.z; csa[3]=t.w;
        }
        float gpv = 1.0f, gsv = 0.0f, gpa = 1.0f, gsa = 0.0f;
#pragma unroll
        for (int i = CPT - 1; i >= 0; --i) {
            gsv = csv[i] + cpv[i] * gsv; gpv = cpv[i] * gpv;
            gsa = csa[i] + cpa[i] * gsa; gpa = cpa[i] * gpa;
        }

        float Qv_, Cv, Qa_, Ca, d0, d1, d2, d3;
        block_suffix_affine(gpv, gsv, gpa, gsa, j,
                            Qv_, Cv, Qa_, Ca, d0, d1, d2, d3);

        float sLv[CPT], sqv[CPT], sL2v[CPT], sLqv[CPT], sq2v[CPT];
        {
            float4 t;
            t = *(const float4*)(ws + 4*NCH + 4*j); sLv[0]=t.x;  sLv[1]=t.y;  sLv[2]=t.z;  sLv[3]=t.w;
            t = *(const float4*)(ws + 5*NCH + 4*j); sqv[0]=t.x;  sqv[1]=t.y;  sqv[2]=t.z;  sqv[3]=t.w;
            t = *(const float4*)(ws + 6*NCH + 4*j); sL2v[0]=t.x; sL2v[1]=t.y; sL2v[2]=t.z; sL2v[3]=t.w;
            t = *(const float4*)(ws + 7*NCH + 4*j); sLqv[0]=t.x; sLqv[1]=t.y; sLqv[2]=t.z; sLqv[3]=t.w;
            t = *(const float4*)(ws + 8*NCH + 4*j); sq2v[0]=t.x; sq2v[1]=t.y; sq2v[2]=t.z; sq2v[3]=t.w;
        }
        double dS = 0.0, dS2 = 0.0;
#pragma unroll
        for (int i = CPT - 1; i >= 0; --i) {
            int g = 4*j + i;
            if (g == c) { bcast[0] = Cv; bcast[1] = Ca; }   // carry INTO our chunk
            dS  += (double)(sLv[i]  + Ca * sqv[i]);
            dS2 += (double)(sL2v[i] + 2.0f * Ca * sLqv[i] + Ca * Ca * sq2v[i]);
            Cv = csv[i] + cpv[i] * Cv;
            Ca = csa[i] + cpa[i] * Ca;
        }
        dS = wave_redd(dS); dS2 = wave_redd(dS2);
        int wid = j >> 6, ln = j & 63;
        if (ln == 0) { rd[wid][0] = dS; rd[wid][1] = dS2; }
        __syncthreads();
        if (j == 0) {
            double S  = rd[0][0] + rd[1][0] + rd[2][0] + rd[3][0];
            double S2 = rd[0][1] + rd[1][1] + rd[2][1] + rd[3][1];
            double n = (double)BTOT;
            double mean = S / n;
            double var = (S2 - S * mean) / (n - 1.0);   // ddof=1
            bcast[2] = (float)mean;
            bcast[3] = (float)(1.0 / sqrt(var));
        }
    }

    // ---- finalize this block's chunk (inputs are L3-resident after K1) ----
    float rr[EPT], vv[EPT + 1], dd[EPT];
    int mm[EPT];
    const float4* r4 = (const float4*)(r + base);
    const float4* v4 = (const float4*)(v + base);
    const int4*   m4 = (const int4*)(mk + base);
#pragma unroll
    for (int k = 0; k < EPT / 4; ++k) {
        float4 a = r4[k];
        rr[4*k] = a.x; rr[4*k+1] = a.y; rr[4*k+2] = a.z; rr[4*k+3] = a.w;
        float4 b = v4[k];
        vv[4*k] = b.x; vv[4*k+1] = b.y; vv[4*k+2] = b.z; vv[4*k+3] = b.w;
        int4 m = m4[k];
        mm[4*k] = m.x; mm[4*k+1] = m.y; mm[4*k+2] = m.z; mm[4*k+3] = m.w;
    }
    vv[EPT] = (base + EPT < BTOT) ? v[base + EPT] : 0.0f;
#pragma unroll
    for (int k = 0; k < EPT; ++k) {
        float m = (float)mm[k];
        dd[k] = rr[k] + kG * m * vv[k + 1] - vv[k];
    }

    float pv = 1.0f, sv = 0.0f, pa = 1.0f, sa = 0.0f;
#pragma unroll
    for (int k = EPT - 1; k >= 0; --k) {
        float m = (float)mm[k];
        float av = kG * m, aa = kGT * m;
        sv = rr[k] + av * sv;
        sa = dd[k] + aa * sa;
        pv *= av; pa *= aa;
    }
    float QrV, CinV, QrA, CinA, u0, u1, u2, u3;
    block_suffix_affine(pv, sv, pa, sa, j,
                        QrV, CinV, QrA, CinA, u0, u1, u2, u3);
    __syncthreads();   // bcast written before this point is visible (scan already synced)

    const float Ccv  = bcast[0];
    const float Cca  = bcast[1];
    const float mean = bcast[2];
    const float inv  = bcast[3];

    float xv = CinV + QrV * Ccv;   // true value at this thread's right boundary
    float xa = CinA + QrA * Cca;
    f4v* a4 = (f4v*)(outA + base);
    f4v* w4 = (f4v*)(outV + base);
#pragma unroll
    for (int g = EPT/4 - 1; g >= 0; --g) {
        float oa[4], ov[4];
#pragma unroll
        for (int k = 3; k >= 0; --k) {
            int idx = 4*g + k;
            float m = (float)mm[idx];
            xv = rr[idx] + kG  * m * xv;
            xa = dd[idx] + kGT * m * xa;
            ov[k] = xv;
            oa[k] = (xa - mean) * inv;
        }
        f4v va = { oa[0], oa[1], oa[2], oa[3] };
        f4v vw = { ov[0], ov[1], ov[2], ov[3] };
        __builtin_nontemporal_store(va, a4 + g);
        __builtin_nontemporal_store(vw, w4 + g);
    }
}

extern "C" void kernel_launch(void* const* d_in, const int* in_sizes, int n_in,
                              void* d_out, int out_size, void* d_ws, size_t ws_size,
                              hipStream_t stream) {
    const float* r  = (const float*)d_in[0];
    const float* v  = (const float*)d_in[1];
    const int*   mk = (const int*)d_in[2];
    float* outA = (float*)d_out;
    float* outV = outA + BTOT;
    float* ws   = (float*)d_ws;

    hipLaunchKernelGGL(ppo_k1_summarize, dim3(NCH), dim3(TPB), 0, stream,
                       r, v, mk, ws);
    hipLaunchKernelGGL(ppo_k2_finalize, dim3(NCH), dim3(TPB), 0, stream,
                       r, v, mk, ws, outA, outV);
}

// Round 5
// 115.494 us; speedup vs baseline: 1.3286x; 1.3286x over previous
//
#include <hip/hip_runtime.h>
#include <math.h>

// Fixed-size problem: B = 4194304
#define BTOT 4194304
#define TPB  256
#define EPT  16                 // elements per thread
#define CS   (TPB * EPT)        // 4096 elements per chunk/block
#define NCH  (BTOT / CS)        // 1024 chunks
#define CPT  (NCH / TPB)        // 4 chunks per thread in the chunk-scan

// ws layout (floats): 9 arrays of NCH chunk summaries
//  0:Pv 1:Sv 2:Pa 3:Sa 4:sL 5:sq 6:sL2 7:sLq 8:sq2

__constant__ const float kG  = 0.99f;
__constant__ const float kGT = 0.99f * 0.95f;

__device__ __forceinline__ float wave_redf(float x) {
#pragma unroll
    for (int o = 32; o > 0; o >>= 1) x += __shfl_down(x, o);
    return x;
}
__device__ __forceinline__ double wave_redd(double x) {
#pragma unroll
    for (int o = 32; o > 0; o >>= 1) x += __shfl_down(x, o);
    return x;
}

// Block-wide suffix scan of affine pairs (P,S) for both recurrences, via
// wave shuffles + one small LDS combine (2 barriers, no 4KB LDS ping-pong).
// Affine map of thread j: x_right -> S + P * x_right.
// Returns:
//   (cpv,csv,cpa,csa) = composition of threads j+1..TPB-1 (identity at j=255)
//   (tpv,tsv,tpa,tsa) = composition of ALL TPB threads (chunk total)
__device__ __forceinline__ void block_suffix_affine(
    float pv, float sv, float pa, float sa, int j,
    float& cpv, float& csv, float& cpa, float& csa,
    float& tpv, float& tsv, float& tpa, float& tsa)
{
    const int ln = j & 63, w = j >> 6;
    __shared__ float wt[4][4];
    __syncthreads();                       // protect wt across repeated calls

    // wave-level inclusive suffix scan (lane ln ends covering ln..63)
#pragma unroll
    for (int o = 1; o < 64; o <<= 1) {
        float qpv = __shfl_down(pv, o), qsv = __shfl_down(sv, o);
        float qpa = __shfl_down(pa, o), qsa = __shfl_down(sa, o);
        if (ln + o < 64) { sv += pv * qsv; pv *= qpv; sa += pa * qsa; pa *= qpa; }
    }
    // exclusive-from-right (lanes ln+1..63)
    float epv = __shfl_down(pv, 1), esv = __shfl_down(sv, 1);
    float epa = __shfl_down(pa, 1), esa = __shfl_down(sa, 1);
    if (ln == 63) { epv = 1.f; esv = 0.f; epa = 1.f; esa = 0.f; }

    if (ln == 0) { wt[w][0] = pv; wt[w][1] = sv; wt[w][2] = pa; wt[w][3] = sa; }
    __syncthreads();

    // rest = totals of waves w+1..3, composed right-to-left
    float rpv = 1.f, rsv = 0.f, rpa = 1.f, rsa = 0.f;
    for (int u = 3; u > w; --u) {
        rsv = wt[u][1] + wt[u][0] * rsv; rpv = wt[u][0] * rpv;
        rsa = wt[u][3] + wt[u][2] * rsa; rpa = wt[u][2] * rpa;
    }
    csv = esv + epv * rsv; cpv = epv * rpv;
    csa = esa + epa * rsa; cpa = epa * rpa;

    // block total = wt[0] o wt[1] o wt[2] o wt[3]
    float t0pv = 1.f, t0sv = 0.f, t0pa = 1.f, t0sa = 0.f;
#pragma unroll
    for (int u = 3; u >= 0; --u) {
        t0sv = wt[u][1] + wt[u][0] * t0sv; t0pv = wt[u][0] * t0pv;
        t0sa = wt[u][3] + wt[u][2] * t0sa; t0pa = wt[u][2] * t0pa;
    }
    tpv = t0pv; tsv = t0sv; tpa = t0pa; tsa = t0sa;
}

// ---------------- K1: per-chunk affine summaries + quadratic stats ---------
__global__ __launch_bounds__(TPB) void ppo_k1_summarize(
    const float* __restrict__ r, const float* __restrict__ v,
    const int* __restrict__ mk, float* __restrict__ ws) {
    const int c = blockIdx.x;
    const int j = threadIdx.x;
    const int base = c * CS + j * EPT;

    float rr[EPT], vv[EPT + 1], dd[EPT];
    int mm[EPT];
    const float4* r4 = (const float4*)(r + base);
    const float4* v4 = (const float4*)(v + base);
    const int4*   m4 = (const int4*)(mk + base);
#pragma unroll
    for (int k = 0; k < EPT / 4; ++k) {
        float4 a = r4[k];
        rr[4*k] = a.x; rr[4*k+1] = a.y; rr[4*k+2] = a.z; rr[4*k+3] = a.w;
        float4 b = v4[k];
        vv[4*k] = b.x; vv[4*k+1] = b.y; vv[4*k+2] = b.z; vv[4*k+3] = b.w;
        int4 m = m4[k];
        mm[4*k] = m.x; mm[4*k+1] = m.y; mm[4*k+2] = m.z; mm[4*k+3] = m.w;
    }
    vv[EPT] = (base + EPT < BTOT) ? v[base + EPT] : 0.0f;

#pragma unroll
    for (int k = 0; k < EPT; ++k) {
        float m = (float)mm[k];
        dd[k] = rr[k] + kG * m * vv[k + 1] - vv[k];
    }

    // per-thread affine summaries (reverse, zero carry)
    float pv = 1.0f, sv = 0.0f, pa = 1.0f, sa = 0.0f;
#pragma unroll
    for (int k = EPT - 1; k >= 0; --k) {
        float m = (float)mm[k];
        float av = kG * m, aa = kGT * m;
        sv = rr[k] + av * sv;
        sa = dd[k] + aa * sa;
        pv *= av; pa *= aa;
    }

    float QrV, CinV, QrA, CinA, chPv, chSv, chPa, chSa;
    block_suffix_affine(pv, sv, pa, sa, j,
                        QrV, CinV, QrA, CinA, chPv, chSv, chPa, chSa);

    // chunk-local A values + quadratic stats: A = L + q * C_chunk
    float x = CinA, ql = 1.0f;
    float s0 = 0, s1 = 0, s2 = 0, s3 = 0, s4 = 0;
#pragma unroll
    for (int k = EPT - 1; k >= 0; --k) {
        float m = (float)mm[k];
        float aa = kGT * m;
        x = dd[k] + aa * x;
        ql *= aa;
        float q = ql * QrA;
        s0 += x; s1 += q; s2 += x * x; s3 += x * q; s4 += q * q;
    }
    s0 = wave_redf(s0); s1 = wave_redf(s1); s2 = wave_redf(s2);
    s3 = wave_redf(s3); s4 = wave_redf(s4);
    __shared__ float rb[4][5];
    int wid = j >> 6, ln = j & 63;
    if (ln == 0) { rb[wid][0]=s0; rb[wid][1]=s1; rb[wid][2]=s2; rb[wid][3]=s3; rb[wid][4]=s4; }
    __syncthreads();
    if (j == 0) {
        float t0=0,t1=0,t2=0,t3=0,t4=0;
        for (int w = 0; w < 4; ++w) { t0+=rb[w][0]; t1+=rb[w][1]; t2+=rb[w][2]; t3+=rb[w][3]; t4+=rb[w][4]; }
        ws[0*NCH+c] = chPv; ws[1*NCH+c] = chSv; ws[2*NCH+c] = chPa; ws[3*NCH+c] = chSa;
        ws[4*NCH+c] = t0;   ws[5*NCH+c] = t1;   ws[6*NCH+c] = t2;
        ws[7*NCH+c] = t3;   ws[8*NCH+c] = t4;
    }
}

// ------- K2: every block redundantly scans chunk summaries, then finalizes
//         its own chunk (inputs re-read, L3-resident). No grid sync. --------
__global__ __launch_bounds__(TPB) void ppo_k2_finalize(
    const float* __restrict__ r, const float* __restrict__ v,
    const int* __restrict__ mk, const float* __restrict__ ws,
    float* __restrict__ outA, float* __restrict__ outV)
{
    const int c = blockIdx.x;
    const int j = threadIdx.x;
    const int base = c * CS + j * EPT;

    __shared__ double rd[4][2];
    __shared__ float bcast[4];   // 0:carryV(into chunk c) 1:carryA 2:mean 3:inv_std

    // ---- redundant chunk-summary scan (identical in every block) ----
    {
        float cpv[CPT], csv[CPT], cpa[CPT], csa[CPT];
        {
            float4 t;
            t = *(const float4*)(ws + 0*NCH + 4*j); cpv[0]=t.x; cpv[1]=t.y; cpv[2]=t.z; cpv[3]=t.w;
            t = *(const float4*)(ws + 1*NCH + 4*j); csv[0]=t.x; csv[1]=t.y; csv[2]=t.z; csv[3]=t.w;
            t = *(const float4*)(ws + 2*NCH + 4*j); cpa[0]=t.x; cpa[1]=t.y; cpa[2]=t.z; cpa[3]=t.w;
            t = *(const float4*)(ws + 3*NCH + 4*j); csa[0]=t.x; csa[1]=t.y; csa[2]=t.z; csa[3]=t.w;
        }
        float gpv = 1.0f, gsv = 0.0f, gpa = 1.0f, gsa = 0.0f;
#pragma unroll
        for (int i = CPT - 1; i >= 0; --i) {
            gsv = csv[i] + cpv[i] * gsv; gpv = cpv[i] * gpv;
            gsa = csa[i] + cpa[i] * gsa; gpa = cpa[i] * gpa;
        }

        float Qv_, Cv, Qa_, Ca, d0, d1, d2, d3;
        block_suffix_affine(gpv, gsv, gpa, gsa, j,
                            Qv_, Cv, Qa_, Ca, d0, d1, d2, d3);

        float sLv[CPT], sqv[CPT], sL2v[CPT], sLqv[CPT], sq2v[CPT];
        {
            float4 t;
            t = *(const float4*)(ws + 4*NCH + 4*j); sLv[0]=t.x;  sLv[1]=t.y;  sLv[2]=t.z;  sLv[3]=t.w;
            t = *(const float4*)(ws + 5*NCH + 4*j); sqv[0]=t.x;  sqv[1]=t.y;  sqv[2]=t.z;  sqv[3]=t.w;
            t = *(const float4*)(ws + 6*NCH + 4*j); sL2v[0]=t.x; sL2v[1]=t.y; sL2v[2]=t.z; sL2v[3]=t.w;
            t = *(const float4*)(ws + 7*NCH + 4*j); sLqv[0]=t.x; sLqv[1]=t.y; sLqv[2]=t.z; sLqv[3]=t.w;
            t = *(const float4*)(ws + 8*NCH + 4*j); sq2v[0]=t.x; sq2v[1]=t.y; sq2v[2]=t.z; sq2v[3]=t.w;
        }
        double dS = 0.0, dS2 = 0.0;
#pragma unroll
        for (int i = CPT - 1; i >= 0; --i) {
            int g = 4*j + i;
            if (g == c) { bcast[0] = Cv; bcast[1] = Ca; }   // carry INTO our chunk
            dS  += (double)(sLv[i]  + Ca * sqv[i]);
            dS2 += (double)(sL2v[i] + 2.0f * Ca * sLqv[i] + Ca * Ca * sq2v[i]);
            Cv = csv[i] + cpv[i] * Cv;
            Ca = csa[i] + cpa[i] * Ca;
        }
        dS = wave_redd(dS); dS2 = wave_redd(dS2);
        int wid = j >> 6, ln = j & 63;
        if (ln == 0) { rd[wid][0] = dS; rd[wid][1] = dS2; }
        __syncthreads();
        if (j == 0) {
            double S  = rd[0][0] + rd[1][0] + rd[2][0] + rd[3][0];
            double S2 = rd[0][1] + rd[1][1] + rd[2][1] + rd[3][1];
            double n = (double)BTOT;
            double mean = S / n;
            double var = (S2 - S * mean) / (n - 1.0);   // ddof=1
            bcast[2] = (float)mean;
            bcast[3] = (float)(1.0 / sqrt(var));
        }
    }

    // ---- finalize this block's chunk (inputs are L3-resident after K1) ----
    float rr[EPT], vv[EPT + 1], dd[EPT];
    int mm[EPT];
    const float4* r4 = (const float4*)(r + base);
    const float4* v4 = (const float4*)(v + base);
    const int4*   m4 = (const int4*)(mk + base);
#pragma unroll
    for (int k = 0; k < EPT / 4; ++k) {
        float4 a = r4[k];
        rr[4*k] = a.x; rr[4*k+1] = a.y; rr[4*k+2] = a.z; rr[4*k+3] = a.w;
        float4 b = v4[k];
        vv[4*k] = b.x; vv[4*k+1] = b.y; vv[4*k+2] = b.z; vv[4*k+3] = b.w;
        int4 m = m4[k];
        mm[4*k] = m.x; mm[4*k+1] = m.y; mm[4*k+2] = m.z; mm[4*k+3] = m.w;
    }
    vv[EPT] = (base + EPT < BTOT) ? v[base + EPT] : 0.0f;
#pragma unroll
    for (int k = 0; k < EPT; ++k) {
        float m = (float)mm[k];
        dd[k] = rr[k] + kG * m * vv[k + 1] - vv[k];
    }

    float pv = 1.0f, sv = 0.0f, pa = 1.0f, sa = 0.0f;
#pragma unroll
    for (int k = EPT - 1; k >= 0; --k) {
        float m = (float)mm[k];
        float av = kG * m, aa = kGT * m;
        sv = rr[k] + av * sv;
        sa = dd[k] + aa * sa;
        pv *= av; pa *= aa;
    }
    float QrV, CinV, QrA, CinA, u0, u1, u2, u3;
    block_suffix_affine(pv, sv, pa, sa, j,
                        QrV, CinV, QrA, CinA, u0, u1, u2, u3);
    __syncthreads();   // ensures bcast[] writes are visible

    const float Ccv  = bcast[0];
    const float Cca  = bcast[1];
    const float mean = bcast[2];
    const float inv  = bcast[3];

    float xv = CinV + QrV * Ccv;   // true value at this thread's right boundary
    float xa = CinA + QrA * Cca;
    float oA[EPT], oV[EPT];
#pragma unroll
    for (int k = EPT - 1; k >= 0; --k) {
        float m = (float)mm[k];
        xv = rr[k] + kG  * m * xv;
        xa = dd[k] + kGT * m * xa;
        oV[k] = xv;
        oA[k] = (xa - mean) * inv;
    }
    float4* a4 = (float4*)(outA + base);
    float4* w4 = (float4*)(outV + base);
#pragma unroll
    for (int k = 0; k < EPT / 4; ++k) {
        a4[k] = make_float4(oA[4*k], oA[4*k+1], oA[4*k+2], oA[4*k+3]);
        w4[k] = make_float4(oV[4*k], oV[4*k+1], oV[4*k+2], oV[4*k+3]);
    }
}

extern "C" void kernel_launch(void* const* d_in, const int* in_sizes, int n_in,
                              void* d_out, int out_size, void* d_ws, size_t ws_size,
                              hipStream_t stream) {
    const float* r  = (const float*)d_in[0];
    const float* v  = (const float*)d_in[1];
    const int*   mk = (const int*)d_in[2];
    float* outA = (float*)d_out;
    float* outV = outA + BTOT;
    float* ws   = (float*)d_ws;

    hipLaunchKernelGGL(ppo_k1_summarize, dim3(NCH), dim3(TPB), 0, stream,
                       r, v, mk, ws);
    hipLaunchKernelGGL(ppo_k2_finalize, dim3(NCH), dim3(TPB), 0, stream,
                       r, v, mk, ws, outA, outV);
}